// Round 1
// baseline (211.197 us; speedup 1.0000x reference)
//
#include <hip/hip_runtime.h>
#include <math.h>

#define N_NODES  100000
#define N_HID    128
#define N_ETYPES 10
#define N_EDGES  100000

// Half-wave (32 lanes) per edge: lane j loads float4 at dim 4*j -> 32*16B = 512B
// per row, fully coalesced. 8 half-waves per 256-thread block, 4 edges per
// half-wave -> 32 edges/block. grid.x = 100000/32 = 3125, grid.y = etype.
#define EDGES_PER_HW 4

__global__ __launch_bounds__(256) void distmult_score_kernel(
    const float* __restrict__ h,
    const float* __restrict__ W,
    const int*   __restrict__ src,
    const int*   __restrict__ dst,
    const int*   __restrict__ rel,
    float*       __restrict__ out)
{
    const int t    = blockIdx.y;
    const int lane = threadIdx.x & 31;                     // lane within half-wave
    const int hw   = (blockIdx.x << 3) + (threadIdx.x >> 5); // half-wave id in etype

    const int r = rel[t];                                   // relation row (== t here)
    const float4 w4 = ((const float4*)(W + (size_t)r * N_HID))[lane];

    const long base = (long)t * N_EDGES;
    const int  e0   = hw * EDGES_PER_HW;

    float res = 0.0f;  // lane k keeps edge k's score

    #pragma unroll
    for (int k = 0; k < EDGES_PER_HW; ++k) {
        const int e = e0 + k;
        const int s = src[base + e];
        const int d = dst[base + e];

        const float4 a = ((const float4*)(h + (size_t)s * N_HID))[lane];
        const float4 b = ((const float4*)(h + (size_t)d * N_HID))[lane];

        float p = a.x * w4.x * b.x
                + a.y * w4.y * b.y
                + a.z * w4.z * b.z
                + a.w * w4.w * b.w;

        // butterfly reduce over the 32-lane group (xor masks < 32 stay in-group)
        p += __shfl_xor(p, 16, 64);
        p += __shfl_xor(p, 8, 64);
        p += __shfl_xor(p, 4, 64);
        p += __shfl_xor(p, 2, 64);
        p += __shfl_xor(p, 1, 64);

        if (lane == k) res = p;
    }

    // lanes 0..3 store 4 consecutive floats (one coalesced 16B burst per half-wave)
    if (lane < EDGES_PER_HW) {
        out[base + e0 + lane] = 1.0f / (1.0f + __expf(-res));
    }
}

extern "C" void kernel_launch(void* const* d_in, const int* in_sizes, int n_in,
                              void* d_out, int out_size, void* d_ws, size_t ws_size,
                              hipStream_t stream) {
    const float* h   = (const float*)d_in[0];
    const float* W   = (const float*)d_in[1];
    const int*   src = (const int*)d_in[2];
    const int*   dst = (const int*)d_in[3];
    const int*   rel = (const int*)d_in[4];
    float*       out = (float*)d_out;

    dim3 grid(N_EDGES / (8 * EDGES_PER_HW), N_ETYPES);  // 3125 x 10
    dim3 block(256);
    distmult_score_kernel<<<grid, block, 0, stream>>>(h, W, src, dst, rel, out);
}

// Round 2
// 156.297 us; speedup vs baseline: 1.3513x; 1.3513x over previous
//
#include <hip/hip_runtime.h>
#include <hip/hip_fp16.h>
#include <math.h>

#define N_NODES  100000
#define N_HID    128
#define N_ETYPES 10
#define N_EDGES  100000

#define EDGES_PER_HW 4

// ---------------- pass 1: h (fp32) -> h16 (fp16) in workspace ----------------
// 12.8M elements, 8 per thread: read 32B, write 16B. ~77MB traffic ~ 13us.
__global__ __launch_bounds__(256) void convert_h_kernel(
    const float* __restrict__ h, __half* __restrict__ h16)
{
    const size_t i = ((size_t)blockIdx.x * 256 + threadIdx.x) * 8;
    const float4 f0 = *(const float4*)(h + i);
    const float4 f1 = *(const float4*)(h + i + 4);
    union { uint4 u; __half2 p[4]; } pk;
    pk.p[0] = __floats2half2_rn(f0.x, f0.y);
    pk.p[1] = __floats2half2_rn(f0.z, f0.w);
    pk.p[2] = __floats2half2_rn(f1.x, f1.y);
    pk.p[3] = __floats2half2_rn(f1.z, f1.w);
    *(uint4*)(h16 + i) = pk.u;
}

// ---------------- pass 2: gather + dot + sigmoid (fp16 rows) ----------------
// Half-wave (32 lanes) per edge; lane j loads 8B (4 halves) at dim 4j ->
// 32*8B = 256B contiguous per row. All 4 edges' rows prefetched before the
// reduce phase to maximize outstanding gathers.
__global__ __launch_bounds__(256) void distmult_score_f16_kernel(
    const __half* __restrict__ h16,
    const float*  __restrict__ W,
    const int*    __restrict__ src,
    const int*    __restrict__ dst,
    const int*    __restrict__ rel,
    float*        __restrict__ out)
{
    const int t    = blockIdx.y;
    const int lane = threadIdx.x & 31;
    const int hw   = (blockIdx.x << 3) + (threadIdx.x >> 5);

    const int r = rel[t];
    const float4 w4 = ((const float4*)(W + (size_t)r * N_HID))[lane];

    const long base = (long)t * N_EDGES;
    const int  e0   = hw * EDGES_PER_HW;

    // phase 1: issue all index loads, then all row loads (independent)
    int sidx[EDGES_PER_HW], didx[EDGES_PER_HW];
    #pragma unroll
    for (int k = 0; k < EDGES_PER_HW; ++k) {
        sidx[k] = src[base + e0 + k];
        didx[k] = dst[base + e0 + k];
    }

    uint2 A[EDGES_PER_HW], B[EDGES_PER_HW];
    #pragma unroll
    for (int k = 0; k < EDGES_PER_HW; ++k) {
        A[k] = ((const uint2*)(h16 + (size_t)sidx[k] * N_HID))[lane];
        B[k] = ((const uint2*)(h16 + (size_t)didx[k] * N_HID))[lane];
    }

    // phase 2: fp32 dot + butterfly reduce over the 32-lane group
    float res = 0.0f;
    #pragma unroll
    for (int k = 0; k < EDGES_PER_HW; ++k) {
        union { uint2 u; __half2 p[2]; } ua, ub;
        ua.u = A[k]; ub.u = B[k];
        const float2 a01 = __half22float2(ua.p[0]);
        const float2 a23 = __half22float2(ua.p[1]);
        const float2 b01 = __half22float2(ub.p[0]);
        const float2 b23 = __half22float2(ub.p[1]);

        float p = a01.x * w4.x * b01.x
                + a01.y * w4.y * b01.y
                + a23.x * w4.z * b23.x
                + a23.y * w4.w * b23.y;

        p += __shfl_xor(p, 16, 64);
        p += __shfl_xor(p, 8, 64);
        p += __shfl_xor(p, 4, 64);
        p += __shfl_xor(p, 2, 64);
        p += __shfl_xor(p, 1, 64);

        if (lane == k) res = p;
    }

    if (lane < EDGES_PER_HW) {
        out[base + e0 + lane] = 1.0f / (1.0f + __expf(-res));
    }
}

// ---------------- fallback (fp32 rows, no workspace) ----------------
__global__ __launch_bounds__(256) void distmult_score_f32_kernel(
    const float* __restrict__ h,
    const float* __restrict__ W,
    const int*   __restrict__ src,
    const int*   __restrict__ dst,
    const int*   __restrict__ rel,
    float*       __restrict__ out)
{
    const int t    = blockIdx.y;
    const int lane = threadIdx.x & 31;
    const int hw   = (blockIdx.x << 3) + (threadIdx.x >> 5);

    const int r = rel[t];
    const float4 w4 = ((const float4*)(W + (size_t)r * N_HID))[lane];

    const long base = (long)t * N_EDGES;
    const int  e0   = hw * EDGES_PER_HW;

    float res = 0.0f;
    #pragma unroll
    for (int k = 0; k < EDGES_PER_HW; ++k) {
        const int e = e0 + k;
        const int s = src[base + e];
        const int d = dst[base + e];
        const float4 a = ((const float4*)(h + (size_t)s * N_HID))[lane];
        const float4 b = ((const float4*)(h + (size_t)d * N_HID))[lane];
        float p = a.x * w4.x * b.x + a.y * w4.y * b.y
                + a.z * w4.z * b.z + a.w * w4.w * b.w;
        p += __shfl_xor(p, 16, 64);
        p += __shfl_xor(p, 8, 64);
        p += __shfl_xor(p, 4, 64);
        p += __shfl_xor(p, 2, 64);
        p += __shfl_xor(p, 1, 64);
        if (lane == k) res = p;
    }
    if (lane < EDGES_PER_HW) {
        out[base + e0 + lane] = 1.0f / (1.0f + __expf(-res));
    }
}

extern "C" void kernel_launch(void* const* d_in, const int* in_sizes, int n_in,
                              void* d_out, int out_size, void* d_ws, size_t ws_size,
                              hipStream_t stream) {
    const float* h   = (const float*)d_in[0];
    const float* W   = (const float*)d_in[1];
    const int*   src = (const int*)d_in[2];
    const int*   dst = (const int*)d_in[3];
    const int*   rel = (const int*)d_in[4];
    float*       out = (float*)d_out;

    const size_t h16_bytes = (size_t)N_NODES * N_HID * sizeof(__half);  // 25.6 MB

    dim3 grid(N_EDGES / (8 * EDGES_PER_HW), N_ETYPES);  // 3125 x 10
    dim3 block(256);

    if (ws_size >= h16_bytes) {
        __half* h16 = (__half*)d_ws;
        const int total = N_NODES * N_HID;               // 12.8M
        convert_h_kernel<<<total / (256 * 8), 256, 0, stream>>>(h, h16);
        distmult_score_f16_kernel<<<grid, block, 0, stream>>>(h16, W, src, dst, rel, out);
    } else {
        distmult_score_f32_kernel<<<grid, block, 0, stream>>>(h, W, src, dst, rel, out);
    }
}

// Round 3
// 155.693 us; speedup vs baseline: 1.3565x; 1.0039x over previous
//
#include <hip/hip_runtime.h>
#include <hip/hip_fp16.h>
#include <math.h>

#define N_NODES  100000
#define N_HID    128
#define N_ETYPES 10
#define N_EDGES  100000

#define EDGES_PER_HW 4

typedef __attribute__((ext_vector_type(2))) _Float16 h2v;

#if defined(__has_builtin)
#if __has_builtin(__builtin_amdgcn_fdot2)
#define HAVE_FDOT2 1
#endif
#endif

__device__ __forceinline__ float dot2acc(h2v a, h2v b, float c) {
#ifdef HAVE_FDOT2
    return __builtin_amdgcn_fdot2(a, b, c, false);
#else
    return c + (float)a.x * (float)b.x + (float)a.y * (float)b.y;
#endif
}

// ---------------- pass 1: h,W (fp32) -> fp16 in workspace ----------------
__global__ __launch_bounds__(256) void convert_kernel(
    const float* __restrict__ h, const float* __restrict__ W,
    __half* __restrict__ h16, __half* __restrict__ W16)
{
    const size_t i = ((size_t)blockIdx.x * 256 + threadIdx.x) * 8;
    const float4 f0 = *(const float4*)(h + i);
    const float4 f1 = *(const float4*)(h + i + 4);
    union { uint4 u; __half2 p[4]; } pk;
    pk.p[0] = __floats2half2_rn(f0.x, f0.y);
    pk.p[1] = __floats2half2_rn(f0.z, f0.w);
    pk.p[2] = __floats2half2_rn(f1.x, f1.y);
    pk.p[3] = __floats2half2_rn(f1.z, f1.w);
    *(uint4*)(h16 + i) = pk.u;

    // W is tiny (1280 elems): block 0, threads 0..159 convert 8 each
    if (blockIdx.x == 0 && threadIdx.x < (N_ETYPES * N_HID / 8)) {
        const size_t j = (size_t)threadIdx.x * 8;
        const float4 g0 = *(const float4*)(W + j);
        const float4 g1 = *(const float4*)(W + j + 4);
        union { uint4 u; __half2 p[4]; } pw;
        pw.p[0] = __floats2half2_rn(g0.x, g0.y);
        pw.p[1] = __floats2half2_rn(g0.z, g0.w);
        pw.p[2] = __floats2half2_rn(g1.x, g1.y);
        pw.p[3] = __floats2half2_rn(g1.z, g1.w);
        *(uint4*)(W16 + j) = pw.u;
    }
}

// ---------------- pass 2: gather + dot + sigmoid (fp16, v_dot2) ----------------
__global__ __launch_bounds__(256) void distmult_score_f16_kernel(
    const __half* __restrict__ h16,
    const __half* __restrict__ W16,
    const int*    __restrict__ src,
    const int*    __restrict__ dst,
    const int*    __restrict__ rel,
    float*        __restrict__ out)
{
    const int t    = blockIdx.y;
    const int lane = threadIdx.x & 31;
    const int hw   = (blockIdx.x << 3) + (threadIdx.x >> 5);

    const int r = rel[t];
    union { uint2 u; h2v p[2]; } uw;
    uw.u = ((const uint2*)(W16 + (size_t)r * N_HID))[lane];

    const long base = (long)t * N_EDGES;
    const int  e0   = hw * EDGES_PER_HW;

    // broadcast loads: 4 consecutive indices in one dwordx4 (same addr all lanes)
    const int4 s4 = *(const int4*)(src + base + e0);
    const int4 d4 = *(const int4*)(dst + base + e0);
    const int sidx[EDGES_PER_HW] = { s4.x, s4.y, s4.z, s4.w };
    const int didx[EDGES_PER_HW] = { d4.x, d4.y, d4.z, d4.w };

    // prefetch all 8 rows (8B/lane each) before reducing
    uint2 A[EDGES_PER_HW], B[EDGES_PER_HW];
    #pragma unroll
    for (int k = 0; k < EDGES_PER_HW; ++k) {
        A[k] = ((const uint2*)(h16 + (size_t)sidx[k] * N_HID))[lane];
        B[k] = ((const uint2*)(h16 + (size_t)didx[k] * N_HID))[lane];
    }

    float res = 0.0f;
    #pragma unroll
    for (int k = 0; k < EDGES_PER_HW; ++k) {
        union { uint2 u; h2v p[2]; } ua, ub;
        ua.u = A[k]; ub.u = B[k];

        // p = sum a*(w*b): v_pk_mul_f16 + v_dot2_f32_f16
        float p = dot2acc(ua.p[0], (h2v)(uw.p[0] * ub.p[0]), 0.0f);
        p = dot2acc(ua.p[1], (h2v)(uw.p[1] * ub.p[1]), p);

        p += __shfl_xor(p, 16, 64);
        p += __shfl_xor(p, 8, 64);
        p += __shfl_xor(p, 4, 64);
        p += __shfl_xor(p, 2, 64);
        p += __shfl_xor(p, 1, 64);

        if (lane == k) res = p;
    }

    if (lane < EDGES_PER_HW) {
        out[base + e0 + lane] = 1.0f / (1.0f + __expf(-res));
    }
}

// ---------------- fallback (fp32 rows, no workspace) ----------------
__global__ __launch_bounds__(256) void distmult_score_f32_kernel(
    const float* __restrict__ h,
    const float* __restrict__ W,
    const int*   __restrict__ src,
    const int*   __restrict__ dst,
    const int*   __restrict__ rel,
    float*       __restrict__ out)
{
    const int t    = blockIdx.y;
    const int lane = threadIdx.x & 31;
    const int hw   = (blockIdx.x << 3) + (threadIdx.x >> 5);
    const int r = rel[t];
    const float4 w4 = ((const float4*)(W + (size_t)r * N_HID))[lane];
    const long base = (long)t * N_EDGES;
    const int  e0   = hw * EDGES_PER_HW;

    float res = 0.0f;
    #pragma unroll
    for (int k = 0; k < EDGES_PER_HW; ++k) {
        const int e = e0 + k;
        const int s = src[base + e];
        const int d = dst[base + e];
        const float4 a = ((const float4*)(h + (size_t)s * N_HID))[lane];
        const float4 b = ((const float4*)(h + (size_t)d * N_HID))[lane];
        float p = a.x * w4.x * b.x + a.y * w4.y * b.y
                + a.z * w4.z * b.z + a.w * w4.w * b.w;
        p += __shfl_xor(p, 16, 64);
        p += __shfl_xor(p, 8, 64);
        p += __shfl_xor(p, 4, 64);
        p += __shfl_xor(p, 2, 64);
        p += __shfl_xor(p, 1, 64);
        if (lane == k) res = p;
    }
    if (lane < EDGES_PER_HW) {
        out[base + e0 + lane] = 1.0f / (1.0f + __expf(-res));
    }
}

extern "C" void kernel_launch(void* const* d_in, const int* in_sizes, int n_in,
                              void* d_out, int out_size, void* d_ws, size_t ws_size,
                              hipStream_t stream) {
    const float* h   = (const float*)d_in[0];
    const float* W   = (const float*)d_in[1];
    const int*   src = (const int*)d_in[2];
    const int*   dst = (const int*)d_in[3];
    const int*   rel = (const int*)d_in[4];
    float*       out = (float*)d_out;

    const size_t h16_elems = (size_t)N_NODES * N_HID;                // 12.8M
    const size_t need = (h16_elems + N_ETYPES * N_HID) * sizeof(__half);

    dim3 grid(N_EDGES / (8 * EDGES_PER_HW), N_ETYPES);  // 3125 x 10
    dim3 block(256);

    if (ws_size >= need) {
        __half* h16 = (__half*)d_ws;
        __half* W16 = h16 + h16_elems;
        convert_kernel<<<(int)(h16_elems / (256 * 8)), 256, 0, stream>>>(h, W, h16, W16);
        distmult_score_f16_kernel<<<grid, block, 0, stream>>>(h16, W16, src, dst, rel, out);
    } else {
        distmult_score_f32_kernel<<<grid, block, 0, stream>>>(h, W, src, dst, rel, out);
    }
}